// Round 1
// 451.261 us; speedup vs baseline: 1.0671x; 1.0671x over previous
//
#include <hip/hip_runtime.h>
#include <math.h>

#define HS 4096
#define NIN 17
#define ROW_CHUNKS 512
#define ROWS_PER_CHUNK (HS / ROW_CHUNKS)   // 8

// Native vector types. vfloat4u carries only 4B alignment: the concatenated
// output buffer puts hebb/et/pw at float offset == 1 (mod 4), so wide stores
// there are dword-aligned only (gfx950 global dwordx4 supports that).
typedef float vfloat4  __attribute__((ext_vector_type(4)));
typedef float vfloat4u __attribute__((ext_vector_type(4), aligned(4)));

__device__ __forceinline__ vfloat4 ntload4(const vfloat4* p) {
  return __builtin_nontemporal_load(p);
}
__device__ __forceinline__ void ntstore4u(vfloat4u* p, vfloat4 v) {
  __builtin_nontemporal_store((vfloat4u)v, p);
}

// Kernel 1: matvec partials of hidden @ (w + alpha*hebb).
// grid (4, 512) x 256. All 24 independent 16B loads are hoisted into
// registers up-front (~115 VGPR) so each thread keeps them all in flight.
// w/alpha are single-use -> nt loads (keep hebb/et/pw L3-resident);
// hebb is re-read by hebb_stream_k -> normal (allocating) load.
__global__ __launch_bounds__(256) void matvec_k(
    const float* __restrict__ hidden, const float* __restrict__ w,
    const float* __restrict__ alpha, const float* __restrict__ hebb,
    float* __restrict__ partial) {
  const int j4 = blockIdx.x * blockDim.x + threadIdx.x;   // float4 col, 0..1023
  const int row0 = blockIdx.y * ROWS_PER_CHUNK;
  const size_t base = (size_t)row0 * (HS / 4) + j4;
  const vfloat4* wp = reinterpret_cast<const vfloat4*>(w) + base;
  const vfloat4* ap = reinterpret_cast<const vfloat4*>(alpha) + base;
  const vfloat4* bp = reinterpret_cast<const vfloat4*>(hebb) + base;

  vfloat4 wv[ROWS_PER_CHUNK], av[ROWS_PER_CHUNK], bv[ROWS_PER_CHUNK];
#pragma unroll
  for (int r = 0; r < ROWS_PER_CHUNK; ++r) {
    wv[r] = ntload4(wp + (size_t)r * (HS / 4));
    av[r] = ntload4(ap + (size_t)r * (HS / 4));
    bv[r] = bp[(size_t)r * (HS / 4)];
  }

  vfloat4 acc = (vfloat4)(0.f);
#pragma unroll
  for (int r = 0; r < ROWS_PER_CHUNK; ++r) {
    const float h = hidden[row0 + r];                      // uniform -> s_load
#pragma unroll
    for (int c = 0; c < 4; ++c)
      acc[c] = fmaf(h, fmaf(av[r][c], bv[r][c], wv[r][c]), acc[c]);
  }
  reinterpret_cast<vfloat4*>(partial)[(size_t)blockIdx.y * (HS / 4) + j4] = acc;
}

// Kernel 2: coalesced reduction of the 512 partials + i2h + bias + tanh.
// 64 blocks x 256 threads: wave lanes read 64 CONSECUTIVE columns of one
// partial row (256B/instruction) instead of a 16KB-stride column walk.
__global__ __launch_bounds__(256) void finalize_k(
    const float* __restrict__ partial, const float* __restrict__ inputs,
    const float* __restrict__ i2h_w, const float* __restrict__ i2h_b,
    float* __restrict__ out_hactiv) {
  const int t = threadIdx.x;
  const int col = blockIdx.x * 64 + (t & 63);
  const int g = t >> 6;                                    // 4 chunk groups
  float acc = 0.f;
#pragma unroll 16
  for (int k = 0; k < ROW_CHUNKS / 4; ++k)
    acc += partial[(size_t)(g * (ROW_CHUNKS / 4) + k) * HS + col];

  __shared__ float red[256];
  red[t] = acc;
  __syncthreads();
  if (t < 64) {
    float s = red[t] + red[t + 64] + red[t + 128] + red[t + 192];
#pragma unroll
    for (int l = 0; l < NIN; ++l)
      s = fmaf(inputs[l], i2h_w[(size_t)col * NIN + l], s);
    out_hactiv[col] = tanhf(s + i2h_b[col]);
  }
}

// Kernel 3: 5 dot products (4 action head rows + value head).
__global__ __launch_bounds__(256) void heads_k(
    const float* __restrict__ hactiv, const float* __restrict__ h2o_w,
    const float* __restrict__ h2o_b, const float* __restrict__ h2v_w,
    const float* __restrict__ h2v_b, float* __restrict__ out) {
  const int r = blockIdx.x;
  const float* wrow = (r < 4) ? (h2o_w + (size_t)r * HS) : h2v_w;
  float s = 0.f;
  for (int j = threadIdx.x; j < HS; j += 256) s = fmaf(hactiv[j], wrow[j], s);
  __shared__ float red[256];
  red[threadIdx.x] = s;
  __syncthreads();
  for (int off = 128; off > 0; off >>= 1) {
    if (threadIdx.x < off) red[threadIdx.x] += red[threadIdx.x + off];
    __syncthreads();
  }
  if (threadIdx.x == 0) out[r] = red[0] + ((r < 4) ? h2o_b[r] : h2v_b[0]);
}

// Kernel 4: hebb_new = (1-eta)*hebb + eta*outer(hidden, hactiv) FUSED with the
// et/pw pass-through. Everything float4. hebb/et/pw reads should be L3-warm
// (nt loads/stores elsewhere preserved residency); all output stores nt.
__global__ __launch_bounds__(256) void hebb_stream_k(
    const float* __restrict__ hebb, const float* __restrict__ hidden,
    const float* __restrict__ hactiv, const float* __restrict__ eta,
    const float* __restrict__ et, const float* __restrict__ pw,
    float* __restrict__ out_hebb, float* __restrict__ out_et,
    float* __restrict__ out_pw) {
  const float e = eta[0];
  const float one_m_e = 1.f - e;
  const vfloat4*  hebbp = reinterpret_cast<const vfloat4*>(hebb);
  const vfloat4*  etp   = reinterpret_cast<const vfloat4*>(et);
  const vfloat4*  pwp   = reinterpret_cast<const vfloat4*>(pw);
  const vfloat4u* hap   = reinterpret_cast<const vfloat4u*>(hactiv);  // base %16 != 0
  vfloat4u* oheb = reinterpret_cast<vfloat4u*>(out_hebb);
  vfloat4u* oet  = reinterpret_cast<vfloat4u*>(out_et);
  vfloat4u* opw  = reinterpret_cast<vfloat4u*>(out_pw);

  // 4096^2/4 = 4,194,304 float4 units; 2048 blocks x 256 thr x 8 units.
  const size_t u0 = (size_t)blockIdx.x * 2048 + threadIdx.x;
#pragma unroll
  for (int i = 0; i < 8; ++i) {
    const size_t u = u0 + (size_t)i * 256;
    const vfloat4 ev = ntload4(etp + u);
    const vfloat4 pv = ntload4(pwp + u);
    const vfloat4 hb = hebbp[u];                 // L3-warm from matvec_k
    const float ehi = e * hidden[u >> 10];       // row = (4u)>>12
    const vfloat4 ha = (vfloat4)hap[u & 1023];   // cols 4*(u&1023)..+3, L1-hot
    vfloat4 o;
#pragma unroll
    for (int c = 0; c < 4; ++c) o[c] = fmaf(one_m_e, hb[c], ehi * ha[c]);
    ntstore4u(oet + u, ev);
    ntstore4u(opw + u, pv);
    ntstore4u(oheb + u, o);
  }
}

extern "C" void kernel_launch(void* const* d_in, const int* in_sizes, int n_in,
                              void* d_out, int out_size, void* d_ws, size_t ws_size,
                              hipStream_t stream) {
  const float* inputs = (const float*)d_in[0];
  const float* hidden = (const float*)d_in[1];
  const float* hebb   = (const float*)d_in[2];
  const float* et     = (const float*)d_in[3];
  const float* pw     = (const float*)d_in[4];
  const float* i2h_w  = (const float*)d_in[5];
  const float* i2h_b  = (const float*)d_in[6];
  const float* w      = (const float*)d_in[7];
  const float* alpha  = (const float*)d_in[8];
  const float* eta    = (const float*)d_in[9];
  const float* h2o_w  = (const float*)d_in[10];
  const float* h2o_b  = (const float*)d_in[11];
  const float* h2v_w  = (const float*)d_in[12];
  const float* h2v_b  = (const float*)d_in[13];

  float* out = (float*)d_out;
  const size_t NSQ = (size_t)HS * HS;
  float* out_heads  = out;               // activout[4] + valueout[1]
  float* out_hactiv = out + 5;           // [HS]
  float* out_hebb   = out + 5 + HS;      // [HS*HS] (float offset 4101)
  float* out_et     = out_hebb + NSQ;
  float* out_pw     = out_et + NSQ;

  // Partial scratch: 512*4096 floats = 8 MB. Prefer d_ws; else an aligned
  // slice of the hebb output region (consumed before hebb_stream_k writes it).
  const size_t need = (size_t)ROW_CHUNKS * HS * sizeof(float);
  float* partial = (ws_size >= need) ? (float*)d_ws
                                     : (out_hebb + 3 /* float off 4104, 16B-aligned */);

  hipLaunchKernelGGL(matvec_k, dim3(HS / 4 / 256, ROW_CHUNKS), dim3(256),
                     0, stream, hidden, w, alpha, hebb, partial);
  hipLaunchKernelGGL(finalize_k, dim3(HS / 64), dim3(256), 0, stream,
                     partial, inputs, i2h_w, i2h_b, out_hactiv);
  hipLaunchKernelGGL(heads_k, dim3(5), dim3(256), 0, stream,
                     out_hactiv, h2o_w, h2o_b, h2v_w, h2v_b, out_heads);
  hipLaunchKernelGGL(hebb_stream_k, dim3(2048), dim3(256), 0, stream,
                     hebb, hidden, out_hactiv, eta, et, pw,
                     out_hebb, out_et, out_pw);
}